// Round 6
// baseline (28.789 us; speedup 1.0000x reference)
//
#include <hip/hip_runtime.h>
#include <math.h>

#define N_RAYS 65536
#define N_SAMPLES 256
#define T_THRESHOLD 1e-4f
#define NEAR_DISTANCE 0.01f

// d_ws layout: float delta[N_RAYS]; delta < 0 means miss.

// ---- DPP helpers: cross-lane adds on the VALU pipe (no LDS traffic) ----
template <int CTRL, int ROW_MASK>
__device__ __forceinline__ float dpp_add(float v) {
    int iv = __builtin_bit_cast(int, v);
    int sh = __builtin_amdgcn_update_dpp(0, iv, CTRL, ROW_MASK, 0xf, false);
    return v + __builtin_bit_cast(float, sh);
}

// Wave64 inclusive scan; lane i holds sum of lanes [0..i], lane 63 the total.
__device__ __forceinline__ float wave_incl_scan(float x) {
    x = dpp_add<0x111, 0xf>(x);   // row_shr:1
    x = dpp_add<0x112, 0xf>(x);   // row_shr:2
    x = dpp_add<0x114, 0xf>(x);   // row_shr:4
    x = dpp_add<0x118, 0xf>(x);   // row_shr:8
    x = dpp_add<0x142, 0xa>(x);   // row_bcast:15 -> rows 1,3
    x = dpp_add<0x143, 0xc>(x);   // row_bcast:31 -> rows 2,3
    return x;
}

// Pass 1: one thread per ray. Reads only `rays` (1.5 MB).
// Writes delta[ray] (<0 for miss) and zeroes the output of miss rays.
__global__ __launch_bounds__(256) void ngp_setup_kernel(
    const float* __restrict__ rays,
    const float* __restrict__ center,
    const float* __restrict__ half_size,
    float* __restrict__ deltas,
    float* __restrict__ out)
{
    const int ray = blockIdx.x * blockDim.x + threadIdx.x;
    if (ray >= N_RAYS) return;

    const float* rp = rays + (size_t)ray * 6;
    float o[3] = { rp[0], rp[1], rp[2] };
    float d[3] = { rp[3], rp[4], rp[5] };
    float inv_norm = 1.0f / (sqrtf(d[0]*d[0] + d[1]*d[1] + d[2]*d[2]) + 1e-8f);
    d[0] *= inv_norm; d[1] *= inv_norm; d[2] *= inv_norm;

    float tmin = -INFINITY, tmax = INFINITY;
    #pragma unroll
    for (int a = 0; a < 3; ++a) {
        float da  = (fabsf(d[a]) > 1e-8f) ? d[a] : 1e-8f;
        float inv = 1.0f / da;
        float t1  = (center[a] - half_size[a] - o[a]) * inv;
        float t2  = (center[a] + half_size[a] - o[a]) * inv;
        tmin = fmaxf(tmin, fminf(t1, t2));
        tmax = fminf(tmax, fmaxf(t1, t2));
    }
    const bool hit = tmax > fmaxf(tmin, 0.0f);

    if (hit) {
        float near = fmaxf(tmin, 0.0f);
        if (near < NEAR_DISTANCE) near = NEAR_DISTANCE;
        deltas[ray] = (tmax - near) * (1.0f / (float)N_SAMPLES);
    } else {
        deltas[ray] = -1.0f;
        float* op = out + (size_t)ray * 3;
        op[0] = 0.0f; op[1] = 0.0f; op[2] = 0.0f;
    }
}

// Pass 2: one wave per ray, in ray order (preserves streaming locality).
// Lane l handles samples [4l, 4l+4). Uses ws_i = T_i - T_{i+1} (5 exps).
__global__ __launch_bounds__(256) void ngp_render_kernel(
    const float* __restrict__ sigmas,    // [N_RAYS, N_SAMPLES]
    const float* __restrict__ rgbs,      // [N_RAYS, N_SAMPLES, 3]
    const float* __restrict__ deltas,    // [N_RAYS]
    float* __restrict__ out)             // [N_RAYS, 3]
{
    const int lane = threadIdx.x & 63;
    const int ray  = __builtin_amdgcn_readfirstlane(
        (blockIdx.x * blockDim.x + threadIdx.x) >> 6);
    if (ray >= N_RAYS) return;

    const float delta = deltas[ray];     // wave-uniform -> scalar load
    if (delta < 0.0f) return;            // miss: output already zeroed in pass 1

    // ---- sigma * delta, local prefix over 4 samples ----
    const float4 sg = *reinterpret_cast<const float4*>(
        sigmas + (size_t)ray * N_SAMPLES + lane * 4);
    const float sd0 = sg.x * delta;
    const float sd1 = sg.y * delta;
    const float sd2 = sg.z * delta;
    const float sd3 = sg.w * delta;
    const float p0 = sd0;
    const float p1 = p0 + sd1;
    const float p2 = p1 + sd2;
    const float p3 = p2 + sd3;        // lane total

    // ---- wave-inclusive scan of lane totals (DPP, VALU-only) ----
    const float incl = wave_incl_scan(p3);
    const float excl = incl - p3;     // exclusive prefix entering this lane

    // ---- transmittance chain: ws_i = alpha_i*T_i = T_i - T_{i+1} ----
    const float T0 = __expf(-excl);
    const float T1 = __expf(-(excl + p0));
    const float T2 = __expf(-(excl + p1));
    const float T3 = __expf(-(excl + p2));
    const float T4 = __expf(-incl);
    const float ws0 = (T0 >= T_THRESHOLD) ? T0 - T1 : 0.0f;
    const float ws1 = (T1 >= T_THRESHOLD) ? T1 - T2 : 0.0f;
    const float ws2 = (T2 >= T_THRESHOLD) ? T2 - T3 : 0.0f;
    const float ws3 = (T3 >= T_THRESHOLD) ? T3 - T4 : 0.0f;

    // ---- rgbs: 48 contiguous bytes per lane, 3 aligned float4 loads ----
    const float* rb = rgbs + (size_t)ray * N_SAMPLES * 3 + (size_t)lane * 12;
    const float4 r0 = *reinterpret_cast<const float4*>(rb + 0);
    const float4 r1 = *reinterpret_cast<const float4*>(rb + 4);
    const float4 r2 = *reinterpret_cast<const float4*>(rb + 8);
    // sample 4l+0 -> (r0.x,r0.y,r0.z)   4l+1 -> (r0.w,r1.x,r1.y)
    // sample 4l+2 -> (r1.z,r1.w,r2.x)   4l+3 -> (r2.y,r2.z,r2.w)
    float R = ws0 * r0.x + ws1 * r0.w + ws2 * r1.z + ws3 * r2.y;
    float G = ws0 * r0.y + ws1 * r1.x + ws2 * r1.w + ws3 * r2.z;
    float B = ws0 * r0.z + ws1 * r1.y + ws2 * r2.x + ws3 * r2.w;

    // ---- wave reduce via DPP scan (total lands in lane 63) ----
    R = wave_incl_scan(R);
    G = wave_incl_scan(G);
    B = wave_incl_scan(B);
    if (lane == 63) {
        float* op = out + (size_t)ray * 3;
        op[0] = R; op[1] = G; op[2] = B;
    }
}

extern "C" void kernel_launch(void* const* d_in, const int* in_sizes, int n_in,
                              void* d_out, int out_size, void* d_ws, size_t ws_size,
                              hipStream_t stream) {
    const float* rays      = (const float*)d_in[0];
    const float* sigmas    = (const float*)d_in[1];
    const float* rgbs      = (const float*)d_in[2];
    const float* center    = (const float*)d_in[3];
    const float* half_size = (const float*)d_in[4];
    float* out    = (float*)d_out;
    float* deltas = (float*)d_ws;     // 256 KB << ws_size

    ngp_setup_kernel<<<N_RAYS / 256, 256, 0, stream>>>(
        rays, center, half_size, deltas, out);

    ngp_render_kernel<<<N_RAYS / 4, 256, 0, stream>>>(
        sigmas, rgbs, deltas, out);
}

// Round 7
// 24.537 us; speedup vs baseline: 1.1733x; 1.1733x over previous
//
#include <hip/hip_runtime.h>
#include <math.h>

#define N_RAYS 65536
#define N_SAMPLES 256
#define T_THRESHOLD 1e-4f
#define NEAR_DISTANCE 0.01f

// ---- DPP helpers: cross-lane adds on the VALU pipe (no LDS traffic) ----
template <int CTRL, int ROW_MASK>
__device__ __forceinline__ float dpp_add(float v) {
    int iv = __builtin_bit_cast(int, v);
    int sh = __builtin_amdgcn_update_dpp(0, iv, CTRL, ROW_MASK, 0xf, false);
    return v + __builtin_bit_cast(float, sh);
}

// Inclusive scan WITHIN each 32-lane half (segmented at the 32-lane
// boundary): the standard wave64 DPP scan minus the final row_bcast:31.
// Lane 31 (resp. 63) ends with its half's total.
__device__ __forceinline__ float half_incl_scan(float x) {
    x = dpp_add<0x111, 0xf>(x);   // row_shr:1
    x = dpp_add<0x112, 0xf>(x);   // row_shr:2
    x = dpp_add<0x114, 0xf>(x);   // row_shr:4
    x = dpp_add<0x118, 0xf>(x);   // row_shr:8
    x = dpp_add<0x142, 0xa>(x);   // row_bcast:15 -> rows 1,3 (stays in half)
    return x;
}

// Two rays per wave: lanes [0,32) handle ray 2w, lanes [32,64) ray 2w+1.
// Lane (s = lane&31) handles samples [8s, 8s+8) of its ray.
// Address stream is identical to the 1-ray/wave version (in ray order,
// hole-punched at misses); per-ray scan/exp/setup overhead is halved.
__global__ __launch_bounds__(256) void ngp_render_kernel(
    const float* __restrict__ rays,      // [N_RAYS, 6]
    const float* __restrict__ sigmas,    // [N_RAYS, N_SAMPLES]
    const float* __restrict__ rgbs,      // [N_RAYS, N_SAMPLES, 3]
    const float* __restrict__ center,    // [3]
    const float* __restrict__ half_size, // [3]
    float* __restrict__ out)             // [N_RAYS, 3]
{
    const int lane   = threadIdx.x & 63;
    const int s      = lane & 31;        // position within half
    const int waveId = (blockIdx.x * blockDim.x + threadIdx.x) >> 6;
    const int ray    = waveId * 2 + (lane >> 5);
    if (ray >= N_RAYS) return;

    // ---- setup: each half computes its own ray's AABB (broadcast loads) ----
    const float* rp = rays + (size_t)ray * 6;
    float o[3] = { rp[0], rp[1], rp[2] };
    float d[3] = { rp[3], rp[4], rp[5] };
    float inv_norm = 1.0f / (sqrtf(d[0]*d[0] + d[1]*d[1] + d[2]*d[2]) + 1e-8f);
    d[0] *= inv_norm; d[1] *= inv_norm; d[2] *= inv_norm;

    float tmin = -INFINITY, tmax = INFINITY;
    #pragma unroll
    for (int a = 0; a < 3; ++a) {
        float da  = (fabsf(d[a]) > 1e-8f) ? d[a] : 1e-8f;
        float inv = 1.0f / da;
        float t1  = (center[a] - half_size[a] - o[a]) * inv;
        float t2  = (center[a] + half_size[a] - o[a]) * inv;
        tmin = fmaxf(tmin, fminf(t1, t2));
        tmax = fminf(tmax, fmaxf(t1, t2));
    }
    const bool hit = tmax > fmaxf(tmin, 0.0f);

    // both rays miss -> write zeros, done (skips all sigma/rgb bytes)
    if (__ballot(hit) == 0ull) {
        if (s == 31) {
            float* op = out + (size_t)ray * 3;
            op[0] = 0.0f; op[1] = 0.0f; op[2] = 0.0f;
        }
        return;
    }

    float delta = 0.0f;
    if (hit) {
        float near = fmaxf(tmin, 0.0f);
        if (near < NEAR_DISTANCE) near = NEAR_DISTANCE;
        delta = (tmax - near) * (1.0f / (float)N_SAMPLES);
    }

    // ---- loads: only hit segments fetch; miss segments keep zeros ----
    float4 sg0 = make_float4(0,0,0,0), sg1 = make_float4(0,0,0,0);
    float4 r0 = sg0, r1 = sg0, r2 = sg0, r3 = sg0, r4 = sg0, r5 = sg0;
    if (hit) {
        const float* sp = sigmas + (size_t)ray * N_SAMPLES + s * 8;
        sg0 = *reinterpret_cast<const float4*>(sp);
        sg1 = *reinterpret_cast<const float4*>(sp + 4);
        const float* rb = rgbs + (size_t)ray * N_SAMPLES * 3 + (size_t)s * 24;
        r0 = *reinterpret_cast<const float4*>(rb + 0);
        r1 = *reinterpret_cast<const float4*>(rb + 4);
        r2 = *reinterpret_cast<const float4*>(rb + 8);
        r3 = *reinterpret_cast<const float4*>(rb + 12);
        r4 = *reinterpret_cast<const float4*>(rb + 16);
        r5 = *reinterpret_cast<const float4*>(rb + 20);
    }

    // ---- sigma*delta, local prefix over 8 samples ----
    const float sd0 = sg0.x * delta, sd1 = sg0.y * delta;
    const float sd2 = sg0.z * delta, sd3 = sg0.w * delta;
    const float sd4 = sg1.x * delta, sd5 = sg1.y * delta;
    const float sd6 = sg1.z * delta, sd7 = sg1.w * delta;
    const float p0 = sd0;
    const float p1 = p0 + sd1;
    const float p2 = p1 + sd2;
    const float p3 = p2 + sd3;
    const float p4 = p3 + sd4;
    const float p5 = p4 + sd5;
    const float p6 = p5 + sd6;
    const float p7 = p6 + sd7;        // lane total

    // ---- segmented inclusive scan of lane totals ----
    const float incl = half_incl_scan(p7);
    const float excl = incl - p7;

    // ---- transmittance chain: ws_i = T_i - T_{i+1} (9 exps / 2 rays) ----
    const float T0 = __expf(-excl);
    const float T1 = __expf(-(excl + p0));
    const float T2 = __expf(-(excl + p1));
    const float T3 = __expf(-(excl + p2));
    const float T4 = __expf(-(excl + p3));
    const float T5 = __expf(-(excl + p4));
    const float T6 = __expf(-(excl + p5));
    const float T7 = __expf(-(excl + p6));
    const float T8 = __expf(-incl);
    const float ws0 = (T0 >= T_THRESHOLD) ? T0 - T1 : 0.0f;
    const float ws1 = (T1 >= T_THRESHOLD) ? T1 - T2 : 0.0f;
    const float ws2 = (T2 >= T_THRESHOLD) ? T2 - T3 : 0.0f;
    const float ws3 = (T3 >= T_THRESHOLD) ? T3 - T4 : 0.0f;
    const float ws4 = (T4 >= T_THRESHOLD) ? T4 - T5 : 0.0f;
    const float ws5 = (T5 >= T_THRESHOLD) ? T5 - T6 : 0.0f;
    const float ws6 = (T6 >= T_THRESHOLD) ? T6 - T7 : 0.0f;
    const float ws7 = (T7 >= T_THRESHOLD) ? T7 - T8 : 0.0f;

    // sample j colors within lane's 24 floats:
    // j=0:(r0.x,y,z) j=1:(r0.w,r1.x,r1.y) j=2:(r1.z,r1.w,r2.x) j=3:(r2.y,z,w)
    // j=4:(r3.x,y,z) j=5:(r3.w,r4.x,r4.y) j=6:(r4.z,r4.w,r5.x) j=7:(r5.y,z,w)
    float R = ws0*r0.x + ws1*r0.w + ws2*r1.z + ws3*r2.y
            + ws4*r3.x + ws5*r3.w + ws6*r4.z + ws7*r5.y;
    float G = ws0*r0.y + ws1*r1.x + ws2*r1.w + ws3*r2.z
            + ws4*r3.y + ws5*r4.x + ws6*r4.w + ws7*r5.z;
    float B = ws0*r0.z + ws1*r1.y + ws2*r2.x + ws3*r2.w
            + ws4*r3.z + ws5*r4.y + ws6*r5.x + ws7*r5.w;

    // ---- segmented reduce (totals land in lanes 31 and 63) ----
    R = half_incl_scan(R);
    G = half_incl_scan(G);
    B = half_incl_scan(B);
    if (s == 31) {
        float* op = out + (size_t)ray * 3;
        op[0] = R; op[1] = G; op[2] = B;   // miss segment: zeros by construction
    }
}

extern "C" void kernel_launch(void* const* d_in, const int* in_sizes, int n_in,
                              void* d_out, int out_size, void* d_ws, size_t ws_size,
                              hipStream_t stream) {
    const float* rays      = (const float*)d_in[0];
    const float* sigmas    = (const float*)d_in[1];
    const float* rgbs      = (const float*)d_in[2];
    const float* center    = (const float*)d_in[3];
    const float* half_size = (const float*)d_in[4];
    float* out = (float*)d_out;

    // 2 rays/wave, 4 waves/block -> 8 rays per block
    const int blocks = N_RAYS / 8;   // 8192
    ngp_render_kernel<<<blocks, 256, 0, stream>>>(
        rays, sigmas, rgbs, center, half_size, out);
}